// Round 8
// baseline (252.581 us; speedup 1.0000x reference)
//
#include <hip/hip_runtime.h>
#include <cstdint>
#include <cstddef>

#define EPSF 1e-6f

typedef __attribute__((ext_vector_type(4))) float f32x4;
typedef __attribute__((ext_vector_type(8))) short s16x8;
typedef union { s16x8 v; unsigned u[4]; } s16x8u;

// intermediate fragment store (u32 offsets into ws):
//   OFF_H .. : H fragments [bb(64)][tile(248)][kk(2)][lane(64)][4]  (31 MB)
//   OFF_L .. : L fragments, written/read for branch1 only            (31 MB)
// tile = row*4 + coltile; fragment lane = q*16 + lm holds channel-pairs
// kk*16+q*4..+3 of pixel col = coltile*16+lm -- exactly the MFMA B-frag
// layout gemm_out consumes with one coalesced dwordx4 per (tile,kk).
#define OFF_H 32768
#define FRAG_N (64 * 248 * 2 * 256)
#define OFF_L (OFF_H + FRAG_N)

// hi/lo dual-bf16 pack via v_cvt_pk_bf16_f32.
static __device__ __forceinline__ void pack2(float a, float b, unsigned& H, unsigned& L) {
    unsigned h, l;
    asm("v_cvt_pk_bf16_f32 %0, %1, %2" : "=v"(h) : "v"(a), "v"(b));
    float ra = a - __uint_as_float(h << 16);
    float rb = b - __uint_as_float(h & 0xffff0000u);
    asm("v_cvt_pk_bf16_f32 %0, %1, %2" : "=v"(l) : "v"(ra), "v"(rb));
    H = h; L = l;
}
static __device__ __forceinline__ unsigned packH(float a, float b) {
    unsigned h;
    asm("v_cvt_pk_bf16_f32 %0, %1, %2" : "=v"(h) : "v"(a), "v"(b));
    return h;
}

// ws layout (4B units):
//   [0    ..  575]  w1n branch0: [c][9] normalized taps (fp32)
//   [576  .. 1151]  w1n branch1
//   [1152 .. 5247]  w2H branch0 [128][32] u32 c-pair hi
//   [5248 .. 9343]  w2L branch0
//   [9344 ..13439]  w2H branch1
//   [13440..17535]  w2L branch1

__global__ __launch_bounds__(256) void prep(const float* __restrict__ w1,
                                            const float* __restrict__ w2,
                                            float* __restrict__ ws) {
    __shared__ float s1row[64];
    __shared__ float red[4];
    __shared__ float rs8[8];
    const int t = threadIdx.x;
    const int lane = t & 63;
    const int wv = t >> 6;
    const int gid = blockIdx.x * 256 + t;

    float s = 0.f;
    #pragma unroll
    for (int i = 0; i < 32; ++i) { float v = w2[t + 256 * i]; s += v * v; }
    #pragma unroll
    for (int d = 32; d > 0; d >>= 1) s += __shfl_xor(s, d);
    if (lane == 0) red[wv] = s;

    if (t < 64) {
        float rs = 0.f;
        #pragma unroll
        for (int k = 0; k < 9; ++k) { float v = w1[t * 9 + k]; rs += v * v; }
        s1row[t] = rs;
    }

    if (blockIdx.x < 16) {
        const int r8 = t >> 5;
        const int e = t & 31;
        const int row = blockIdx.x * 8 + r8;
        float v0 = w2[row * 64 + e];
        float v1 = w2[row * 64 + 32 + e];
        float rr = v0 * v0 + v1 * v1;
        #pragma unroll
        for (int d = 16; d > 0; d >>= 1) rr += __shfl_down(rr, d);
        if (e == 0) rs8[r8] = rr;
    }
    __syncthreads();

    const float t2 = red[0] + red[1] + red[2] + red[3];
    float a = s1row[lane];
    #pragma unroll
    for (int d = 32; d > 0; d >>= 1) a += __shfl_xor(a, d);
    const float t1 = a;

    unsigned* wsu = (unsigned*)ws;
    if (gid < 4096) {
        const int row = gid >> 5;
        const int cp = gid & 31;
        float v0 = w2[row * 64 + 2 * cp];
        float v1 = w2[row * 64 + 2 * cp + 1];
        float q0 = v0 * v0, q1 = v1 * v1;
        const float rs = rs8[t >> 5];
        unsigned H, L;
        pack2(q0 / t2, q1 / t2, H, L);
        wsu[1152 + row * 32 + cp] = H;
        wsu[5248 + row * 32 + cp] = L;
        pack2(q0 / rs, q1 / rs, H, L);
        wsu[9344 + row * 32 + cp] = H;
        wsu[13440 + row * 32 + cp] = L;
    } else if (gid < 4672) {
        const int i = gid - 4096;
        const int c = i / 9;
        const int k = i - c * 9;
        float v = w1[i];
        float q = v * v;
        ws[c * 9 + k] = q / t1;
        ws[576 + c * 9 + k] = q / s1row[c];
    }
}

// ---- kernel A: depthwise 3x3 + pack, NO LDS, NO barrier ----
// grid (32, 2, 31) x 512. Thread: one c-pair, rows h0/h0+1, 4 px.
// Writes H (and L for branch1) straight into MFMA-fragment layout in ws.
// Each 128B line of the fragment region is written entirely by one wave
// (j=q_a spans the 4 dwords, lm_a&3 spans lmf) -> full-line L2 merge.
__global__ __launch_bounds__(512) void conv_pack(const float* __restrict__ x,
                                                 const float* __restrict__ ws,
                                                 float* __restrict__ wso) {
    const int b = blockIdx.x;
    const int branch = blockIdx.y;
    const int hg = blockIdx.z;
    const int h0 = hg * 2;
    const int t = threadIdx.x;
    const int lane = t & 63;
    const int w = t >> 6;
    const int lm = lane & 15;
    const int q = lane >> 4;
    const bool dual = (branch != 0);

    const float* __restrict__ w1n = ws + branch * 576;
    const float* __restrict__ xb = x + (size_t)(b * 2 + branch) * (64 * 4096);

    const int cpair = w * 4 + q;
    const int c0 = 2 * cpair;
    const float* xp = xb + c0 * 4096 + h0 * 64;
    const int x0 = 4 * lm;
    const int xe = (lm < 15) ? x0 + 4 : 60;   // tail clamp; feeds only px>=62 (junk, finite)

    float pa[2][4], pb[2][4];

    // channel a
    {
        float4 va[4]; float2 ea[4];
        #pragma unroll
        for (int r = 0; r < 4; ++r) va[r] = *(const float4*)(xp + r * 64 + x0);
        #pragma unroll
        for (int r = 0; r < 4; ++r) ea[r] = *(const float2*)(xp + r * 64 + xe);

        const float* wc0 = w1n + c0 * 9;
        if (dual) {
            #pragma unroll
            for (int r = 0; r < 4; ++r) {
                va[r].x = __logf(va[r].x + EPSF); va[r].y = __logf(va[r].y + EPSF);
                va[r].z = __logf(va[r].z + EPSF); va[r].w = __logf(va[r].w + EPSF);
                ea[r].x = __logf(ea[r].x + EPSF); ea[r].y = __logf(ea[r].y + EPSF);
            }
        }
        #pragma unroll
        for (int row = 0; row < 2; ++row) {
            #pragma unroll
            for (int rr = 0; rr < 3; ++rr) {
                const float4 u = va[row + rr];
                const float e0 = ea[row + rr].x, e1 = ea[row + rr].y;
                const float t0 = wc0[rr * 3], t1_ = wc0[rr * 3 + 1], t2_ = wc0[rr * 3 + 2];
                if (rr == 0) {
                    pa[row][0] = u.x * t0 + u.y * t1_ + u.z * t2_;
                    pa[row][1] = u.y * t0 + u.z * t1_ + u.w * t2_;
                    pa[row][2] = u.z * t0 + u.w * t1_ + e0 * t2_;
                    pa[row][3] = u.w * t0 + e0 * t1_ + e1 * t2_;
                } else {
                    pa[row][0] += u.x * t0 + u.y * t1_ + u.z * t2_;
                    pa[row][1] += u.y * t0 + u.z * t1_ + u.w * t2_;
                    pa[row][2] += u.z * t0 + u.w * t1_ + e0 * t2_;
                    pa[row][3] += u.w * t0 + e0 * t1_ + e1 * t2_;
                }
            }
        }
    }
    // channel b
    {
        float4 vb[4]; float2 eb[4];
        #pragma unroll
        for (int r = 0; r < 4; ++r) vb[r] = *(const float4*)(xp + 4096 + r * 64 + x0);
        #pragma unroll
        for (int r = 0; r < 4; ++r) eb[r] = *(const float2*)(xp + 4096 + r * 64 + xe);

        const float* wc1 = w1n + c0 * 9 + 9;
        if (dual) {
            #pragma unroll
            for (int r = 0; r < 4; ++r) {
                vb[r].x = __logf(vb[r].x + EPSF); vb[r].y = __logf(vb[r].y + EPSF);
                vb[r].z = __logf(vb[r].z + EPSF); vb[r].w = __logf(vb[r].w + EPSF);
                eb[r].x = __logf(eb[r].x + EPSF); eb[r].y = __logf(eb[r].y + EPSF);
            }
        }
        #pragma unroll
        for (int row = 0; row < 2; ++row) {
            #pragma unroll
            for (int rr = 0; rr < 3; ++rr) {
                const float4 u = vb[row + rr];
                const float e0 = eb[row + rr].x, e1 = eb[row + rr].y;
                const float t0 = wc1[rr * 3], t1_ = wc1[rr * 3 + 1], t2_ = wc1[rr * 3 + 2];
                if (rr == 0) {
                    pb[row][0] = u.x * t0 + u.y * t1_ + u.z * t2_;
                    pb[row][1] = u.y * t0 + u.z * t1_ + u.w * t2_;
                    pb[row][2] = u.z * t0 + u.w * t1_ + e0 * t2_;
                    pb[row][3] = u.w * t0 + e0 * t1_ + e1 * t2_;
                } else {
                    pb[row][0] += u.x * t0 + u.y * t1_ + u.z * t2_;
                    pb[row][1] += u.y * t0 + u.z * t1_ + u.w * t2_;
                    pb[row][2] += u.z * t0 + u.w * t1_ + e0 * t2_;
                    pb[row][3] += u.w * t0 + e0 * t1_ + e1 * t2_;
                }
            }
        }
    }

    // pack + fragment-layout stores
    unsigned* __restrict__ wsu = (unsigned*)wso;
    const int bb = b * 2 + branch;
    const int kk = cpair >> 4;
    const int qd = (cpair >> 2) & 3;
    const int j  = cpair & 3;
    const int ct = lm >> 2;                 // coltile (constant per thread)
    const int lf0 = (lm & 3) * 4;           // lmf base; lmf = lf0 + i
    #pragma unroll
    for (int row = 0; row < 2; ++row) {
        const int tile = (h0 + row) * 4 + ct;
        const unsigned blk = (((unsigned)(bb * 248 + tile)) * 2 + kk) * 256 + qd * 64 + lf0 * 4 + j;
        #pragma unroll
        for (int i = 0; i < 4; ++i) {
            if (dual) {
                unsigned H, L;
                pack2(pa[row][i], pb[row][i], H, L);
                wsu[OFF_H + blk + i * 4] = H;
                wsu[OFF_L + blk + i * 4] = L;
            } else {
                wsu[OFF_H + blk + i * 4] = packH(pa[row][i], pb[row][i]);
            }
        }
    }
}

// ---- kernel B: pure GEMM from fragments, NO LDS, NO barrier ----
// grid (32, 2, 62) x 512. Block = (b, branch, output row).
// Wave w: 16-oc tile (oc0=w*16) x 64 px. B-frags: one coalesced dwordx4 per
// (coltile, kk) from ws (LLC-hot, just written by conv_pack).
__global__ __launch_bounds__(512) void gemm_out(const float* __restrict__ ws,
                                                float* __restrict__ out) {
    const int b = blockIdx.x;
    const int branch = blockIdx.y;
    const int row = blockIdx.z;            // 0..61
    const int t = threadIdx.x;
    const int lane = t & 63;
    const int w = __builtin_amdgcn_readfirstlane(t >> 6);
    const int lm = lane & 15;
    const int q = lane >> 4;
    const bool dual = (branch != 0);
    const int bb = b * 2 + branch;

    const unsigned* __restrict__ wsu = (const unsigned*)ws;
    const unsigned* __restrict__ w2H = wsu + 1152 + branch * 8192;
    const unsigned* __restrict__ w2L = w2H + 4096;

    const int oc0 = w * 16;

    // A fragments
    s16x8u aH[2], aL[2];
    #pragma unroll
    for (int kk = 0; kk < 2; ++kk) {
        const int off = (oc0 + lm) * 32 + kk * 16 + q * 4;
        #pragma unroll
        for (int jj = 0; jj < 4; ++jj) aH[kk].u[jj] = w2H[off + jj];
    }
    if (dual) {
        #pragma unroll
        for (int kk = 0; kk < 2; ++kk) {
            const int off = (oc0 + lm) * 32 + kk * 16 + q * 4;
            #pragma unroll
            for (int jj = 0; jj < 4; ++jj) aL[kk].u[jj] = w2L[off + jj];
        }
    }

    const unsigned rowbase = (unsigned)(bb * 248 + row * 4);   // tile = rowbase + nt

    f32x4 acc[4];
    #pragma unroll
    for (int nt = 0; nt < 4; ++nt) acc[nt] = (f32x4){0.f, 0.f, 0.f, 0.f};

    if (dual) {
        #pragma unroll
        for (int nt = 0; nt < 4; ++nt) {
            #pragma unroll
            for (int kk = 0; kk < 2; ++kk) {
                const unsigned fb = ((rowbase + nt) * 2 + kk) * 256 + lane * 4;
                s16x8u bH, bL;
                #pragma unroll
                for (int jj = 0; jj < 4; ++jj) bH.u[jj] = wsu[OFF_H + fb + jj];
                #pragma unroll
                for (int jj = 0; jj < 4; ++jj) bL.u[jj] = wsu[OFF_L + fb + jj];
                acc[nt] = __builtin_amdgcn_mfma_f32_16x16x32_bf16(aH[kk].v, bH.v, acc[nt], 0, 0, 0);
                acc[nt] = __builtin_amdgcn_mfma_f32_16x16x32_bf16(aH[kk].v, bL.v, acc[nt], 0, 0, 0);
                acc[nt] = __builtin_amdgcn_mfma_f32_16x16x32_bf16(aL[kk].v, bH.v, acc[nt], 0, 0, 0);
            }
        }
    } else {
        #pragma unroll
        for (int nt = 0; nt < 4; ++nt) {
            #pragma unroll
            for (int kk = 0; kk < 2; ++kk) {
                const unsigned fb = ((rowbase + nt) * 2 + kk) * 256 + lane * 4;
                s16x8u bH;
                #pragma unroll
                for (int jj = 0; jj < 4; ++jj) bH.u[jj] = wsu[OFF_H + fb + jj];
                acc[nt] = __builtin_amdgcn_mfma_f32_16x16x32_bf16(aH[kk].v, bH.v, acc[nt], 0, 0, 0);
            }
        }
    }

    // epilogue: D row = oc (q*4+r), col = nt*16+lm
    const int ocr = oc0 + q * 4;
    #pragma unroll
    for (int nt = 0; nt < 4; ++nt) {
        const int col = nt * 16 + lm;
        if (col < 62) {
            const size_t base =
                ((size_t)(bb * 128 + ocr)) * 3844 + (size_t)row * 62 + col;
            #pragma unroll
            for (int r = 0; r < 4; ++r) {
                float v = acc[nt][r];
                if (dual) v = __expf(v);
                out[base + (size_t)r * 3844] = v;
            }
        }
    }
}

extern "C" void kernel_launch(void* const* d_in, const int* in_sizes, int n_in,
                              void* d_out, int out_size, void* d_ws, size_t ws_size,
                              hipStream_t stream) {
    const float* x  = (const float*)d_in[0];
    const float* w1 = (const float*)d_in[1];
    const float* w2 = (const float*)d_in[2];
    float* out = (float*)d_out;
    float* ws  = (float*)d_ws;

    prep<<<19, 256, 0, stream>>>(w1, w2, ws);

    dim3 gA(32, 2, 31);
    conv_pack<<<gA, 512, 0, stream>>>(x, ws, ws);

    dim3 gB(32, 2, 62);
    gemm_out<<<gB, 512, 0, stream>>>(ws, out);
}

// Round 9
// 195.515 us; speedup vs baseline: 1.2919x; 1.2919x over previous
//
#include <hip/hip_runtime.h>
#include <cstdint>
#include <cstddef>

#define EPSF 1e-6f

typedef __attribute__((ext_vector_type(4))) float f32x4;
typedef __attribute__((ext_vector_type(8))) short s16x8;
typedef union { s16x8 v; unsigned u[4]; } s16x8u;

// hi/lo dual-bf16 pack via v_cvt_pk_bf16_f32 (1 inst packs 2 floats).
// Residual is computed against the EXACT decode (bf16<<16), so any rounding
// mode in cvt_pk is absorbed by the lo term.
static __device__ __forceinline__ void pack2(float a, float b, unsigned& H, unsigned& L) {
    unsigned h, l;
    asm("v_cvt_pk_bf16_f32 %0, %1, %2" : "=v"(h) : "v"(a), "v"(b));
    float ra = a - __uint_as_float(h << 16);
    float rb = b - __uint_as_float(h & 0xffff0000u);
    asm("v_cvt_pk_bf16_f32 %0, %1, %2" : "=v"(l) : "v"(ra), "v"(rb));
    H = h; L = l;
}
static __device__ __forceinline__ unsigned packH(float a, float b) {
    unsigned h;
    asm("v_cvt_pk_bf16_f32 %0, %1, %2" : "=v"(h) : "v"(a), "v"(b));
    return h;
}

// ws layout (4B units):
//   [0    ..  575]  w1n branch0: [c][9] normalized taps (fp32)
//   [576  .. 1151]  w1n branch1
//   [1152 .. 5247]  w2H branch0 [128][32] u32 c-pair hi
//   [5248 .. 9343]  w2L branch0 [128][32] u32 c-pair lo
//   [9344 ..13439]  w2H branch1
//   [13440..17535]  w2L branch1

__global__ __launch_bounds__(256) void prep(const float* __restrict__ w1,
                                            const float* __restrict__ w2,
                                            float* __restrict__ ws) {
    __shared__ float s1row[64];
    __shared__ float red[4];
    __shared__ float rs8[8];
    const int t = threadIdx.x;
    const int lane = t & 63;
    const int wv = t >> 6;
    const int gid = blockIdx.x * 256 + t;

    float s = 0.f;
    #pragma unroll
    for (int i = 0; i < 32; ++i) { float v = w2[t + 256 * i]; s += v * v; }
    #pragma unroll
    for (int d = 32; d > 0; d >>= 1) s += __shfl_xor(s, d);
    if (lane == 0) red[wv] = s;

    if (t < 64) {
        float rs = 0.f;
        #pragma unroll
        for (int k = 0; k < 9; ++k) { float v = w1[t * 9 + k]; rs += v * v; }
        s1row[t] = rs;
    }

    if (blockIdx.x < 16) {
        const int r8 = t >> 5;            // 0..7
        const int e = t & 31;
        const int row = blockIdx.x * 8 + r8;
        float v0 = w2[row * 64 + e];
        float v1 = w2[row * 64 + 32 + e];
        float rr = v0 * v0 + v1 * v1;
        #pragma unroll
        for (int d = 16; d > 0; d >>= 1) rr += __shfl_down(rr, d);
        if (e == 0) rs8[r8] = rr;
    }
    __syncthreads();

    const float t2 = red[0] + red[1] + red[2] + red[3];
    float a = s1row[lane];
    #pragma unroll
    for (int d = 32; d > 0; d >>= 1) a += __shfl_xor(a, d);
    const float t1 = a;

    unsigned* wsu = (unsigned*)ws;
    if (gid < 4096) {
        const int row = gid >> 5;
        const int cp = gid & 31;
        float v0 = w2[row * 64 + 2 * cp];
        float v1 = w2[row * 64 + 2 * cp + 1];
        float q0 = v0 * v0, q1 = v1 * v1;
        const float rs = rs8[t >> 5];
        unsigned H, L;
        pack2(q0 / t2, q1 / t2, H, L);
        wsu[1152 + row * 32 + cp] = H;
        wsu[5248 + row * 32 + cp] = L;
        pack2(q0 / rs, q1 / rs, H, L);
        wsu[9344 + row * 32 + cp] = H;
        wsu[13440 + row * 32 + cp] = L;
    } else if (gid < 4672) {
        const int i = gid - 4096;
        const int c = i / 9;
        const int k = i - c * 9;
        float v = w1[i];
        float q = v * v;
        ws[c * 9 + k] = q / t1;
        ws[576 + c * 9 + k] = q / s1row[c];
    }
}

// grid: 1984 x 1 (1-D), block 512 (8 waves). Per-block work IDENTICAL to the
// round-1 kernel (best measured: 197.6 us). ONE change: (b,branch,hg) derived
// from blockIdx.x with an ODD chunk (31), so co-resident blocks on a CU
// (delta-bid ~ 256) frequently differ in branch -> short branch0 blocks mix
// with long branch1 blocks per CU, breaking the lockstep barrier convoy
// (r6 counters: all pipes idle 73% with synchronized stalls; r1's even
// chunking kept co-resident blocks same-branch/same-phase).
__global__ __launch_bounds__(512) void conv_fused(const float* __restrict__ x,
                                                  const float* __restrict__ ws,
                                                  float* __restrict__ out) {
    const int bid = blockIdx.x;
    const int cid = bid / 31;              // 0..63
    const int hg = bid - cid * 31;         // 0..30
    const int b = cid >> 1;
    const int branch = cid & 1;
    const int h0 = hg * 2;
    const int t = threadIdx.x;
    const int lane = t & 63;
    const int w = __builtin_amdgcn_readfirstlane(t >> 6);
    const int lm = lane & 15;
    const int q = lane >> 4;
    const bool dual = (branch != 0);

    __shared__ unsigned rotH[128 * 33];
    __shared__ unsigned rotL[128 * 33];

    const float* __restrict__ w1n = ws + branch * 576;
    const unsigned* __restrict__ wsu = (const unsigned*)ws;
    const unsigned* __restrict__ w2H = wsu + 1152 + branch * 8192;
    const unsigned* __restrict__ w2L = w2H + 4096;
    const float* __restrict__ xb = x + (size_t)(b * 2 + branch) * (64 * 4096);

    const int woc = (w & 3) * 32;
    const int half = w >> 2;
    const int cpair = w * 4 + q;
    const int c0 = 2 * cpair;

    s16x8u aH[2][2], aL[2][2];

    // ---- phase 1: depthwise 3x3 on 2 channels, 2 output rows ----
    {
        const float* xp0 = xb + c0 * 4096 + h0 * 64 + 4 * lm;
        float4 va[4], vb[4];
        #pragma unroll
        for (int r = 0; r < 4; ++r) va[r] = *(const float4*)(xp0 + r * 64);
        #pragma unroll
        for (int r = 0; r < 4; ++r) vb[r] = *(const float4*)(xp0 + 4096 + r * 64);
        if (dual) {
            #pragma unroll
            for (int r = 0; r < 4; ++r) {
                va[r].x = __logf(va[r].x + EPSF); va[r].y = __logf(va[r].y + EPSF);
                va[r].z = __logf(va[r].z + EPSF); va[r].w = __logf(va[r].w + EPSF);
                vb[r].x = __logf(vb[r].x + EPSF); vb[r].y = __logf(vb[r].y + EPSF);
                vb[r].z = __logf(vb[r].z + EPSF); vb[r].w = __logf(vb[r].w + EPSF);
            }
        }
        float sax[4], say[4], sbx[4], sby[4];
        #pragma unroll
        for (int r = 0; r < 4; ++r) {
            sax[r] = __shfl_down(va[r].x, 1); say[r] = __shfl_down(va[r].y, 1);
            sbx[r] = __shfl_down(vb[r].x, 1); sby[r] = __shfl_down(vb[r].y, 1);
        }
        const float* wc0 = w1n + c0 * 9;
        const float* wc1 = wc0 + 9;
        float pa[2][4], pb[2][4];
        #pragma unroll
        for (int row = 0; row < 2; ++row) {
            #pragma unroll
            for (int rr = 0; rr < 3; ++rr) {
                const float4 u = va[row + rr];
                const float ux1 = sax[row + rr], uy1 = say[row + rr];
                const float t0 = wc0[rr * 3], t1_ = wc0[rr * 3 + 1], t2_ = wc0[rr * 3 + 2];
                if (rr == 0) {
                    pa[row][0] = u.x * t0 + u.y * t1_ + u.z * t2_;
                    pa[row][1] = u.y * t0 + u.z * t1_ + u.w * t2_;
                    pa[row][2] = u.z * t0 + u.w * t1_ + ux1 * t2_;
                    pa[row][3] = u.w * t0 + ux1 * t1_ + uy1 * t2_;
                } else {
                    pa[row][0] += u.x * t0 + u.y * t1_ + u.z * t2_;
                    pa[row][1] += u.y * t0 + u.z * t1_ + u.w * t2_;
                    pa[row][2] += u.z * t0 + u.w * t1_ + ux1 * t2_;
                    pa[row][3] += u.w * t0 + ux1 * t1_ + uy1 * t2_;
                }
            }
            #pragma unroll
            for (int rr = 0; rr < 3; ++rr) {
                const float4 u = vb[row + rr];
                const float ux1 = sbx[row + rr], uy1 = sby[row + rr];
                const float t0 = wc1[rr * 3], t1_ = wc1[rr * 3 + 1], t2_ = wc1[rr * 3 + 2];
                if (rr == 0) {
                    pb[row][0] = u.x * t0 + u.y * t1_ + u.z * t2_;
                    pb[row][1] = u.y * t0 + u.z * t1_ + u.w * t2_;
                    pb[row][2] = u.z * t0 + u.w * t1_ + ux1 * t2_;
                    pb[row][3] = u.w * t0 + ux1 * t1_ + uy1 * t2_;
                } else {
                    pb[row][0] += u.x * t0 + u.y * t1_ + u.z * t2_;
                    pb[row][1] += u.y * t0 + u.z * t1_ + u.w * t2_;
                    pb[row][2] += u.z * t0 + u.w * t1_ + ux1 * t2_;
                    pb[row][3] += u.w * t0 + ux1 * t1_ + uy1 * t2_;
                }
            }
        }

        // ---- A-fragment loads issued HERE: L2 latency hides under the
        //      pack + LDS-write tail instead of being exposed at the barrier.
        #pragma unroll
        for (int mt = 0; mt < 2; ++mt) {
            #pragma unroll
            for (int kk = 0; kk < 2; ++kk) {
                const int off = (woc + mt * 16 + lm) * 32 + kk * 16 + q * 4;
                const unsigned* ph = w2H + off;
                #pragma unroll
                for (int j = 0; j < 4; ++j) aH[mt][kk].u[j] = ph[j];
            }
        }
        if (dual) {
            #pragma unroll
            for (int mt = 0; mt < 2; ++mt) {
                #pragma unroll
                for (int kk = 0; kk < 2; ++kk) {
                    const int off = (woc + mt * 16 + lm) * 32 + kk * 16 + q * 4;
                    const unsigned* pl = w2L + off;
                    #pragma unroll
                    for (int j = 0; j < 4; ++j) aL[mt][kk].u[j] = pl[j];
                }
            }
        }

        #pragma unroll
        for (int row = 0; row < 2; ++row) {
            #pragma unroll
            for (int i = 0; i < 4; ++i) {
                const int pxl = row * 64 + 4 * lm + i;
                if (dual) {
                    unsigned H, L;
                    pack2(pa[row][i], pb[row][i], H, L);
                    rotH[pxl * 33 + cpair] = H;
                    rotL[pxl * 33 + cpair] = L;
                } else {
                    rotH[pxl * 33 + cpair] = packH(pa[row][i], pb[row][i]);
                }
            }
        }
    }
    __syncthreads();

    // ---- phase 2: MFMA GEMM, wave tile = 32 oc x 64 px (one output row) ----
    f32x4 acc[2][4];
    #pragma unroll
    for (int mt = 0; mt < 2; ++mt)
        #pragma unroll
        for (int nt = 0; nt < 4; ++nt)
            acc[mt][nt] = (f32x4){0.f, 0.f, 0.f, 0.f};

    __builtin_amdgcn_s_setprio(1);
    if (dual) {
        #pragma unroll
        for (int nt = 0; nt < 4; ++nt) {
            #pragma unroll
            for (int kk = 0; kk < 2; ++kk) {
                const int idx = (half * 64 + nt * 16 + lm) * 33 + kk * 16 + q * 4;
                s16x8u bH, bL;
                #pragma unroll
                for (int j = 0; j < 4; ++j) bH.u[j] = rotH[idx + j];
                #pragma unroll
                for (int j = 0; j < 4; ++j) bL.u[j] = rotL[idx + j];
                #pragma unroll
                for (int mt = 0; mt < 2; ++mt) {
                    acc[mt][nt] = __builtin_amdgcn_mfma_f32_16x16x32_bf16(aH[mt][kk].v, bH.v, acc[mt][nt], 0, 0, 0);
                    acc[mt][nt] = __builtin_amdgcn_mfma_f32_16x16x32_bf16(aH[mt][kk].v, bL.v, acc[mt][nt], 0, 0, 0);
                    acc[mt][nt] = __builtin_amdgcn_mfma_f32_16x16x32_bf16(aL[mt][kk].v, bH.v, acc[mt][nt], 0, 0, 0);
                }
            }
        }
    } else {
        #pragma unroll
        for (int nt = 0; nt < 4; ++nt) {
            #pragma unroll
            for (int kk = 0; kk < 2; ++kk) {
                const int idx = (half * 64 + nt * 16 + lm) * 33 + kk * 16 + q * 4;
                s16x8u bH;
                #pragma unroll
                for (int j = 0; j < 4; ++j) bH.u[j] = rotH[idx + j];
                #pragma unroll
                for (int mt = 0; mt < 2; ++mt) {
                    acc[mt][nt] = __builtin_amdgcn_mfma_f32_16x16x32_bf16(aH[mt][kk].v, bH.v, acc[mt][nt], 0, 0, 0);
                }
            }
        }
    }
    __builtin_amdgcn_s_setprio(0);

    // ---- epilogue: D row = oc (q*4+reg), col = nt*16+lm, out row h0+half ----
    #pragma unroll
    for (int mt = 0; mt < 2; ++mt) {
        const int oc0 = woc + mt * 16 + q * 4;
        #pragma unroll
        for (int nt = 0; nt < 4; ++nt) {
            const int col = nt * 16 + lm;
            if (col < 62) {
                const size_t base =
                    ((size_t)((b * 2 + branch) * 128 + oc0)) * 3844 +
                    (size_t)(h0 + half) * 62 + col;
                #pragma unroll
                for (int r = 0; r < 4; ++r) {
                    float v = acc[mt][nt][r];
                    if (dual) v = __expf(v);
                    out[base + (size_t)r * 3844] = v;
                }
            }
        }
    }
}

extern "C" void kernel_launch(void* const* d_in, const int* in_sizes, int n_in,
                              void* d_out, int out_size, void* d_ws, size_t ws_size,
                              hipStream_t stream) {
    const float* x  = (const float*)d_in[0];
    const float* w1 = (const float*)d_in[1];
    const float* w2 = (const float*)d_in[2];
    float* out = (float*)d_out;
    float* ws  = (float*)d_ws;

    prep<<<19, 256, 0, stream>>>(w1, w2, ws);

    conv_fused<<<1984, 512, 0, stream>>>(x, ws, out);
}